// Round 4
// baseline (2466.215 us; speedup 1.0000x reference)
//
#include <hip/hip_runtime.h>

typedef _Float16 half8 __attribute__((ext_vector_type(8)));
typedef float floatx4 __attribute__((ext_vector_type(4)));
typedef float floatx2 __attribute__((ext_vector_type(2)));

#define B_   8
#define N_   4096
#define S_   2048
#define K_   64
#define CIN  64
#define HID_ 128
#define Q_   (B_*S_)

// ---------------- ws layout (bytes), total ~2.26 MB ----------------
#define WS_STATS 0u          // 512 u64 (sum0,sq0,sum1,sq1) = 4096
#define WS_CNTT  4096u       // int, padded
#define WS_W0T   4224u       // 128*96 f16 = 24576
#define WS_W1T   28800u      // 128*128 f16 = 32768
#define WS_W2T   61568u      // 32768
#define WS_SC0   94336u      // 128 f32
#define WS_SH0   94848u
#define WS_SC1   95360u
#define WS_SH1   95872u
#define WS_CNT   96384u      // 16384 int = 65536
#define WS_NBR   161920u     // 16384*64 u16 = 2097152
// end ~2259072

// ---------------------------------------------------------------- prep
__global__ __launch_bounds__(256) void k_prep(const float* __restrict__ W0,
        const float* __restrict__ W1, const float* __restrict__ W2,
        _Float16* __restrict__ w0t, _Float16* __restrict__ w1t, _Float16* __restrict__ w2t,
        unsigned long long* __restrict__ stats, int* __restrict__ cntT) {
    int t = blockIdx.x * 256 + threadIdx.x;
    if (t < 128 * 96) {                       // W0T[c][k], k padded 67->96 with 0
        int c = t / 96, k = t - c * 96;
        w0t[t] = (k < 67) ? (_Float16)W0[k * 128 + c] : (_Float16)0.f;
    } else if (t < 128 * 96 + 16384) {        // W1T[c][k]
        int u = t - 128 * 96; int c = u >> 7, k = u & 127;
        w1t[u] = (_Float16)W1[k * 128 + c];
    } else if (t < 128 * 96 + 32768) {        // W2T[c][k]
        int u = t - 128 * 96 - 16384; int c = u >> 7, k = u & 127;
        w2t[u] = (_Float16)W2[k * 128 + c];
    }
    if (t < 512) stats[t] = 0ULL;
    if (t == 0) *cntT = 0;
}

// ---------------------------------------------------------------- FPS
// 8 blocks x 256 threads, 16 pts/thread (blocked -> wave w owns points
// [1024w, 1024w+1024)). Per-iter critical path minimized:
//  - packed-f32 (float2) distance update: same IEEE per-element rounding as
//    scalar numpy order -> selection bit-exact; ~half the VALU issue.
//  - two-phase argmax: float DPP max (cheap) -> readlane broadcast -> exact
//    equality match -> u32 index-key DPP max. First-index tie-break == numpy.
//  - wave leader pre-reads its candidate's coords BEFORE the barrier into
//    redC, so the post-barrier path is ONE parallel LDS read batch
//    (redF+redK+redC[0..3]) + ~30 VALU, not two serial LDS round-trips.
//  - no global stores in the loop; ONE barrier/iter, double-buffered slots.
template<int CTRL>
__device__ inline float dppmaxf(float v) {
    int iv = __builtin_bit_cast(int, v);
    int sh = __builtin_amdgcn_update_dpp(iv, iv, CTRL, 0xF, 0xF, false);
    return fmaxf(v, __builtin_bit_cast(float, sh));
}
template<int CTRL>
__device__ inline unsigned dppmaxu(unsigned v) {
    int iv = (int)v;
    int sh = __builtin_amdgcn_update_dpp(iv, iv, CTRL, 0xF, 0xF, false);
    unsigned s = (unsigned)sh;
    return v > s ? v : s;
}

__global__ __launch_bounds__(256) void k_fps(const float* __restrict__ pos,
        float* __restrict__ outCtr, float* __restrict__ outBatch) {
    __shared__ __align__(16) float4 sP4[N_];                  // 64 KB
    __shared__ __align__(16) float    redF[2][4];
    __shared__ __align__(16) unsigned redK[2][4];
    __shared__ __align__(16) float4   redC[2][4];
    __shared__ unsigned short sSeq[S_];                       // 4 KB
    int b = blockIdx.x, tid = threadIdx.x;
    int lane = tid & 63, wid = tid >> 6;
    const float* P = pos + (size_t)b * N_ * 3;

    floatx2 PX[8], PY[8], PZ[8], MD[8];
    {
        const float4* vp = (const float4*)(P + tid * 48);
        float a[48];
        #pragma unroll
        for (int v = 0; v < 12; v++) {
            float4 t4 = vp[v];
            a[v*4] = t4.x; a[v*4+1] = t4.y; a[v*4+2] = t4.z; a[v*4+3] = t4.w;
        }
        #pragma unroll
        for (int k = 0; k < 8; k++) {
            PX[k][0] = a[6*k];   PY[k][0] = a[6*k+1]; PZ[k][0] = a[6*k+2];
            PX[k][1] = a[6*k+3]; PY[k][1] = a[6*k+4]; PZ[k][1] = a[6*k+5];
            MD[k][0] = __builtin_inff(); MD[k][1] = __builtin_inff();
            sP4[tid * 16 + 2*k]     = make_float4(PX[k][0], PY[k][0], PZ[k][0], 0.f);
            sP4[tid * 16 + 2*k + 1] = make_float4(PX[k][1], PY[k][1], PZ[k][1], 0.f);
        }
    }
    __syncthreads();

    int last = 0;
    float ccx = sP4[0].x, ccy = sP4[0].y, ccz = sP4[0].z;
    for (int i = 0; i < S_; i++) {
        if (tid == (i & 255)) sSeq[i] = (unsigned short)last;
        // ---- packed distance update (bit-exact: per-element IEEE, numpy order, no fma)
        {
            #pragma clang fp contract(off)
            floatx2 cx2 = {ccx, ccx}, cy2 = {ccy, ccy}, cz2 = {ccz, ccz};
            #pragma unroll
            for (int k = 0; k < 8; k++) {
                floatx2 dx = PX[k] - cx2, dy = PY[k] - cy2, dz = PZ[k] - cz2;
                floatx2 d = (dx * dx + dy * dy) + dz * dz;
                MD[k] = __builtin_elementwise_min(MD[k], d);
            }
        }
        // ---- phase 1: float max over lane's 16, then wave DPP max
        floatx2 m2 = MD[0];
        #pragma unroll
        for (int k = 1; k < 8; k++) m2 = __builtin_elementwise_max(m2, MD[k]);
        float m = fmaxf(m2[0], m2[1]);
        m = dppmaxf<0x111>(m);   // row_shr:1
        m = dppmaxf<0x112>(m);   // row_shr:2
        m = dppmaxf<0x114>(m);   // row_shr:4
        m = dppmaxf<0x118>(m);   // row_shr:8
        m = dppmaxf<0x142>(m);   // row_bcast:15
        m = dppmaxf<0x143>(m);   // row_bcast:31 -> lane63 = wave max
        float wmax = __builtin_bit_cast(float,
                __builtin_amdgcn_readlane(__builtin_bit_cast(int, m), 63));
        // ---- phase 2: exact-equality first-index key, wave DPP max
        unsigned msk = 0;
        #pragma unroll
        for (int k = 0; k < 8; k++) {
            msk |= (MD[k][0] == wmax) ? (1u << (2*k))     : 0u;
            msk |= (MD[k][1] == wmax) ? (1u << (2*k + 1)) : 0u;
        }
        unsigned lkey = msk ? (0xFFFFu - (unsigned)(tid * 16 + __builtin_ctz(msk))) : 0u;
        lkey = dppmaxu<0x111>(lkey);
        lkey = dppmaxu<0x112>(lkey);
        lkey = dppmaxu<0x114>(lkey);
        lkey = dppmaxu<0x118>(lkey);
        lkey = dppmaxu<0x142>(lkey);
        lkey = dppmaxu<0x143>(lkey);
        if (lane == 63) {   // pre-read candidate coords: off the post-barrier path
            int widx = (int)(0xFFFFu - lkey);
            float4 c = sP4[widx];
            redF[i & 1][wid] = m;
            redK[i & 1][wid] = lkey;
            redC[i & 1][wid] = c;
        }
        __syncthreads();   // double-buffered slots: one barrier/iter is race-free
        // ---- combine 4 wave candidates (all reads parallel, broadcast)
        float4 f  = *(const float4*)&redF[i & 1][0];
        uint4  kk = *(const uint4*)&redK[i & 1][0];
        float4 c0 = redC[i & 1][0], c1 = redC[i & 1][1];
        float4 c2 = redC[i & 1][2], c3 = redC[i & 1][3];
        float g = fmaxf(fmaxf(f.x, f.y), fmaxf(f.z, f.w));
        unsigned key = 0;
        key = max(key, (f.x == g) ? kk.x : 0u);
        key = max(key, (f.y == g) ? kk.y : 0u);
        key = max(key, (f.z == g) ? kk.z : 0u);
        key = max(key, (f.w == g) ? kk.w : 0u);
        int idx = (int)(0xFFFFu - key);
        int w = idx >> 10;
        float ax = (w & 1) ? c1.x : c0.x, bx = (w & 1) ? c3.x : c2.x;
        float ay = (w & 1) ? c1.y : c0.y, by = (w & 1) ? c3.y : c2.y;
        float az = (w & 1) ? c1.z : c0.z, bz = (w & 1) ? c3.z : c2.z;
        ccx = (w & 2) ? bx : ax; ccy = (w & 2) ? by : ay; ccz = (w & 2) ? bz : az;
        last = idx;
    }
    __syncthreads();
    for (int i = tid; i < S_; i += 256) {    // bulk write-out (once)
        int o = b * S_ + i;
        float4 c = sP4[sSeq[i]];
        outCtr[o*3] = c.x; outCtr[o*3+1] = c.y; outCtr[o*3+2] = c.z;
        outBatch[o] = (float)b;
    }
}

// ---------------------------------------------------------------- radius-KNN (exact rank select)
__global__ __launch_bounds__(256) void k_nbr(const float* __restrict__ pos,
        const float* __restrict__ ctr, unsigned short* __restrict__ nbr,
        int* __restrict__ cnt, int* __restrict__ cntT) {
    __shared__ float cD[1024];
    __shared__ int   cI[1024];
    __shared__ int   cN;
    int q = blockIdx.x, tid = threadIdx.x;
    int b = q >> 11;
    if (tid == 0) cN = 0;
    __syncthreads();
    float cx = ctr[q*3], cy = ctr[q*3+1], cz = ctr[q*3+2];
    const float* P = pos + (size_t)b * N_ * 3;
    {
        #pragma clang fp contract(off)
        for (int j = tid; j < N_; j += 256) {
            float dx = cx - P[j*3], dy = cy - P[j*3+1], dz = cz - P[j*3+2];
            float d2 = (dx * dx + dy * dy) + dz * dz;
            if (d2 <= 0.04f) {                       // f32(0.2**2) boundary, exact
                int s = atomicAdd(&cN, 1);
                if (s < 1024) { cD[s] = d2; cI[s] = j; }
            }
        }
    }
    __syncthreads();
    int M = min(cN, 1024);
    int V = min(M, K_);
    for (int i = tid; i < M; i += 256) {
        float di = cD[i]; int ii = cI[i]; int r = 0;
        for (int j = 0; j < M; j++) {
            float dj = cD[j];
            r += (dj < di) || (dj == di && cI[j] < ii);   // stable top_k tie-break
        }
        if (r < K_) nbr[q * K_ + r] = (unsigned short)ii; // rank IS the slot: deterministic
    }
    if (tid == 0) { cnt[q] = V; atomicAdd(cntT, V); }
}

// ---------------------------------------------------------------- BN params
__global__ void k_bnparam(const unsigned long long* __restrict__ stats, const int* __restrict__ cntT,
        const float* __restrict__ g, const float* __restrict__ be,
        float* __restrict__ scale, float* __restrict__ shift) {
    int t = threadIdx.x;
    double c = (double)(*cntT);
    double mean = (double)(long long)stats[t] * (1.0 / 1048576.0) / c;
    double ex2  = (double)(long long)stats[128 + t] * (1.0 / 1048576.0) / c;
    double var = ex2 - mean * mean;
    if (var < 0.0) var = 0.0;
    double sc = (double)g[t] / sqrt(var + 1e-5);
    scale[t] = (float)sc;
    shift[t] = (float)((double)be[t] - mean * sc);
}

// ---------------------------------------------------------------- fused MLP pass (recompute pipeline)
// STAGE 0: gather+GEMM0 -> stats0
// STAGE 1: ... +BN0/ReLU+GEMM1 -> stats1
// STAGE 2: ... +BN1/ReLU+GEMM2 -> max->out
template<int STAGE>
__global__ __launch_bounds__(256) void k_mlp(const float* __restrict__ x,
        const float* __restrict__ pos, const float* __restrict__ ctr,
        const unsigned short* __restrict__ nbr, const int* __restrict__ cnt,
        const _Float16* __restrict__ w0t, const _Float16* __restrict__ w1t,
        const _Float16* __restrict__ w2t,
        const float* __restrict__ b0, const float* __restrict__ b1,
        const float* __restrict__ b2,
        const float* __restrict__ sc0, const float* __restrict__ sh0,
        const float* __restrict__ sc1, const float* __restrict__ sh1,
        unsigned long long* __restrict__ statsOut, float* __restrict__ outF) {
    __shared__ __align__(16) _Float16 sW0[128 * 104];
    __shared__ __align__(16) _Float16 sW1[(STAGE >= 1) ? 128 * 136 : 8];
    __shared__ __align__(16) _Float16 sW2[(STAGE >= 2) ? 128 * 136 : 8];
    __shared__ __align__(16) _Float16 sBuf[64 * 136];   // feat(104) / h'(136) stage
    __shared__ float sSum[(STAGE <= 1) ? 512 : 4];
    __shared__ float sSq [(STAGE <= 1) ? 512 : 4];
    __shared__ float sMax[(STAGE == 2) ? 512 : 4];
    __shared__ unsigned short sNbr[64];
    __shared__ float sB0v[128];
    __shared__ float sB1v[(STAGE >= 1) ? 128 : 4];
    __shared__ float sSc0[(STAGE >= 1) ? 128 : 4];
    __shared__ float sSh0[(STAGE >= 1) ? 128 : 4];
    __shared__ float sB2v[(STAGE >= 2) ? 128 : 4];
    __shared__ float sSc1[(STAGE >= 2) ? 128 : 4];
    __shared__ float sSh1[(STAGE >= 2) ? 128 : 4];

    int tid = threadIdx.x, wid = tid >> 6, lane = tid & 63;
    int lr = lane & 15, lq = lane >> 4;

    {   // stage W0T (stride 104 f16 = 52 dwords: conflict-spread)
        const unsigned* src = (const unsigned*)w0t;
        unsigned* dst = (unsigned*)sW0;
        for (int i = tid; i < 6144; i += 256) { int r = i / 48, c = i - r * 48; dst[r*52 + c] = src[i]; }
    }
    if constexpr (STAGE >= 1) {
        const unsigned* src = (const unsigned*)w1t;
        unsigned* dst = (unsigned*)sW1;
        for (int i = tid; i < 8192; i += 256) { int r = i >> 6, c = i & 63; dst[r*68 + c] = src[i]; }
    }
    if constexpr (STAGE >= 2) {
        const unsigned* src = (const unsigned*)w2t;
        unsigned* dst = (unsigned*)sW2;
        for (int i = tid; i < 8192; i += 256) { int r = i >> 6, c = i & 63; dst[r*68 + c] = src[i]; }
    }
    if (tid < 128) {
        sB0v[tid] = b0[tid];
        if constexpr (STAGE >= 1) { sB1v[tid] = b1[tid]; sSc0[tid] = sc0[tid]; sSh0[tid] = sh0[tid]; }
        if constexpr (STAGE >= 2) { sB2v[tid] = b2[tid]; sSc1[tid] = sc1[tid]; sSh1[tid] = sh1[tid]; }
    }
    if constexpr (STAGE <= 1)
        for (int i = tid; i < 512; i += 256) { sSum[i] = 0.f; sSq[i] = 0.f; }

    for (int qq = 0; qq < 8; qq++) {
        int q = blockIdx.x * 8 + qq;
        int b = q >> 11;
        __syncthreads();                    // prior-iter sBuf readers done
        int n = cnt[q];
        if (tid < 64) sNbr[tid] = nbr[q * K_ + tid];
        __syncthreads();
        {   // gather x_j -> feat cols 0..63 (f16), zero rows >= n
            int row = tid >> 2, c4 = (tid & 3) * 16;
            half8 o0, o1;
            #pragma unroll
            for (int e = 0; e < 8; e++) { o0[e] = (_Float16)0.f; o1[e] = (_Float16)0.f; }
            if (row < n) {
                const float4* xr = (const float4*)(x + ((size_t)b * N_ + sNbr[row]) * CIN + c4);
                float4 v0 = xr[0], v1 = xr[1], v2 = xr[2], v3 = xr[3];
                o0[0]=(_Float16)v0.x; o0[1]=(_Float16)v0.y; o0[2]=(_Float16)v0.z; o0[3]=(_Float16)v0.w;
                o0[4]=(_Float16)v1.x; o0[5]=(_Float16)v1.y; o0[6]=(_Float16)v1.z; o0[7]=(_Float16)v1.w;
                o1[0]=(_Float16)v2.x; o1[1]=(_Float16)v2.y; o1[2]=(_Float16)v2.z; o1[3]=(_Float16)v2.w;
                o1[4]=(_Float16)v3.x; o1[5]=(_Float16)v3.y; o1[6]=(_Float16)v3.z; o1[7]=(_Float16)v3.w;
            }
            *(half8*)&sBuf[row * 104 + c4]     = o0;
            *(half8*)&sBuf[row * 104 + c4 + 8] = o1;
        }
        if (tid < 64) {   // cols 64..66 = pos_j - ctr, 67..95 = 0
            half8 z, o;
            #pragma unroll
            for (int e = 0; e < 8; e++) { z[e] = (_Float16)0.f; o[e] = (_Float16)0.f; }
            if (tid < n) {
                int j = sNbr[tid];
                float cx = ctr[q*3], cy = ctr[q*3+1], cz = ctr[q*3+2];
                const float* pj = pos + ((size_t)b * N_ + j) * 3;
                o[0] = (_Float16)(pj[0] - cx); o[1] = (_Float16)(pj[1] - cy); o[2] = (_Float16)(pj[2] - cz);
            }
            *(half8*)&sBuf[tid * 104 + 64] = o;
            *(half8*)&sBuf[tid * 104 + 72] = z;
            *(half8*)&sBuf[tid * 104 + 80] = z;
            *(half8*)&sBuf[tid * 104 + 88] = z;
        }
        __syncthreads();

        // ---- GEMM0: K=96
        floatx4 acc[8];
        #pragma unroll
        for (int nt = 0; nt < 8; nt++)
            #pragma unroll
            for (int r = 0; r < 4; r++) acc[nt][r] = 0.f;
        #pragma unroll
        for (int ks = 0; ks < 3; ks++) {
            half8 av = *(const half8*)&sBuf[(wid * 16 + lr) * 104 + ks * 32 + lq * 8];
            #pragma unroll
            for (int nt = 0; nt < 8; nt++) {
                half8 bv = *(const half8*)&sW0[(nt * 16 + lr) * 104 + ks * 32 + lq * 8];
                acc[nt] = __builtin_amdgcn_mfma_f32_16x16x32_f16(av, bv, acc[nt], 0, 0, 0);
            }
        }
        __syncthreads();                    // all waves done reading feat
        int r0 = wid * 16 + lq * 4;

        if constexpr (STAGE == 0) {
            #pragma unroll
            for (int nt = 0; nt < 8; nt++) {
                int col = nt * 16 + lr;
                float bias = sB0v[col];
                float s1 = 0.f, s2 = 0.f;
                #pragma unroll
                for (int r = 0; r < 4; r++) {
                    float v = acc[nt][r] + bias;
                    if (r0 + r < n) { s1 += v; s2 += v * v; }
                }
                s1 += __shfl_xor(s1, 16); s1 += __shfl_xor(s1, 32);
                s2 += __shfl_xor(s2, 16); s2 += __shfl_xor(s2, 32);
                if (lq == 0) { sSum[wid * 128 + col] += s1; sSq[wid * 128 + col] += s2; }
            }
        } else {
            // BN0 + ReLU -> f16 A-matrix for GEMM1
            #pragma unroll
            for (int nt = 0; nt < 8; nt++) {
                int col = nt * 16 + lr;
                float bias = sB0v[col], s = sSc0[col], t2 = sSh0[col];
                #pragma unroll
                for (int r = 0; r < 4; r++) {
                    float v = (acc[nt][r] + bias) * s + t2;
                    sBuf[(r0 + r) * 136 + col] = (_Float16)fmaxf(v, 0.f);
                }
            }
            __syncthreads();
            // ---- GEMM1: K=128
            #pragma unroll
            for (int nt = 0; nt < 8; nt++)
                #pragma unroll
                for (int r = 0; r < 4; r++) acc[nt][r] = 0.f;
            #pragma unroll
            for (int ks = 0; ks < 4; ks++) {
                half8 av = *(const half8*)&sBuf[(wid * 16 + lr) * 136 + ks * 32 + lq * 8];
                #pragma unroll
                for (int nt = 0; nt < 8; nt++) {
                    half8 bv = *(const half8*)&sW1[(nt * 16 + lr) * 136 + ks * 32 + lq * 8];
                    acc[nt] = __builtin_amdgcn_mfma_f32_16x16x32_f16(av, bv, acc[nt], 0, 0, 0);
                }
            }
            __syncthreads();

            if constexpr (STAGE == 1) {
                #pragma unroll
                for (int nt = 0; nt < 8; nt++) {
                    int col = nt * 16 + lr;
                    float bias = sB1v[col];
                    float s1 = 0.f, s2 = 0.f;
                    #pragma unroll
                    for (int r = 0; r < 4; r++) {
                        float v = acc[nt][r] + bias;
                        if (r0 + r < n) { s1 += v; s2 += v * v; }
                    }
                    s1 += __shfl_xor(s1, 16); s1 += __shfl_xor(s1, 32);
                    s2 += __shfl_xor(s2, 16); s2 += __shfl_xor(s2, 32);
                    if (lq == 0) { sSum[wid * 128 + col] += s1; sSq[wid * 128 + col] += s2; }
                }
            } else {
                // BN1 + ReLU -> f16 A-matrix for GEMM2
                #pragma unroll
                for (int nt = 0; nt < 8; nt++) {
                    int col = nt * 16 + lr;
                    float bias = sB1v[col], s = sSc1[col], t2 = sSh1[col];
                    #pragma unroll
                    for (int r = 0; r < 4; r++) {
                        float v = (acc[nt][r] + bias) * s + t2;
                        sBuf[(r0 + r) * 136 + col] = (_Float16)fmaxf(v, 0.f);
                    }
                }
                __syncthreads();
                // ---- GEMM2: K=128
                #pragma unroll
                for (int nt = 0; nt < 8; nt++)
                    #pragma unroll
                    for (int r = 0; r < 4; r++) acc[nt][r] = 0.f;
                #pragma unroll
                for (int ks = 0; ks < 4; ks++) {
                    half8 av = *(const half8*)&sBuf[(wid * 16 + lr) * 136 + ks * 32 + lq * 8];
                    #pragma unroll
                    for (int nt = 0; nt < 8; nt++) {
                        half8 bv = *(const half8*)&sW2[(nt * 16 + lr) * 136 + ks * 32 + lq * 8];
                        acc[nt] = __builtin_amdgcn_mfma_f32_16x16x32_f16(av, bv, acc[nt], 0, 0, 0);
                    }
                }
                // masked max -> out
                #pragma unroll
                for (int nt = 0; nt < 8; nt++) {
                    int col = nt * 16 + lr;
                    float bias = sB2v[col];
                    float m = -__builtin_inff();
                    #pragma unroll
                    for (int r = 0; r < 4; r++)
                        if (r0 + r < n) m = fmaxf(m, acc[nt][r] + bias);
                    m = fmaxf(m, __shfl_xor(m, 16));
                    m = fmaxf(m, __shfl_xor(m, 32));
                    if (lq == 0) sMax[wid * 128 + col] = m;
                }
                __syncthreads();
                if (tid < 128) {
                    float m = fmaxf(fmaxf(sMax[tid], sMax[128 + tid]),
                                    fmaxf(sMax[256 + tid], sMax[384 + tid]));
                    outF[(size_t)q * 128 + tid] = m;
                }
            }
        }
    }
    if constexpr (STAGE <= 1) {
        __syncthreads();
        if (tid < 128) {   // fixed-point (2^20) i64 atomics: fast + deterministic
            float t1 = sSum[tid] + sSum[128 + tid] + sSum[256 + tid] + sSum[384 + tid];
            float t2 = sSq[tid] + sSq[128 + tid] + sSq[256 + tid] + sSq[384 + tid];
            atomicAdd(&statsOut[tid],       (unsigned long long)(long long)llrintf(t1 * 1048576.f));
            atomicAdd(&statsOut[128 + tid], (unsigned long long)(long long)llrintf(t2 * 1048576.f));
        }
    }
}

// ---------------------------------------------------------------- launch
extern "C" void kernel_launch(void* const* d_in, const int* in_sizes, int n_in,
                              void* d_out, int out_size, void* d_ws, size_t ws_size,
                              hipStream_t stream) {
    const float* x   = (const float*)d_in[0];
    const float* pos = (const float*)d_in[1];
    const float* W0  = (const float*)d_in[3];
    const float* b0  = (const float*)d_in[4];
    const float* g0  = (const float*)d_in[5];
    const float* be0 = (const float*)d_in[6];
    const float* W1  = (const float*)d_in[7];
    const float* b1  = (const float*)d_in[8];
    const float* g1  = (const float*)d_in[9];
    const float* be1 = (const float*)d_in[10];
    const float* W2  = (const float*)d_in[11];
    const float* b2  = (const float*)d_in[12];

    char* ws = (char*)d_ws;
    unsigned long long* stats = (unsigned long long*)(ws + WS_STATS);
    int* cntT = (int*)(ws + WS_CNTT);
    _Float16* w0t = (_Float16*)(ws + WS_W0T);
    _Float16* w1t = (_Float16*)(ws + WS_W1T);
    _Float16* w2t = (_Float16*)(ws + WS_W2T);
    float* sc0 = (float*)(ws + WS_SC0);
    float* sh0 = (float*)(ws + WS_SH0);
    float* sc1 = (float*)(ws + WS_SC1);
    float* sh1 = (float*)(ws + WS_SH1);
    int* cnt = (int*)(ws + WS_CNT);
    unsigned short* nbr = (unsigned short*)(ws + WS_NBR);

    float* outF = (float*)d_out;                  // [16384,128]
    float* outCtr = (float*)d_out + 2097152;      // [16384,3]
    float* outBatch = (float*)d_out + 2146304;    // [16384]

    k_prep<<<176, 256, 0, stream>>>(W0, W1, W2, w0t, w1t, w2t, stats, cntT);
    k_fps<<<B_, 256, 0, stream>>>(pos, outCtr, outBatch);
    k_nbr<<<Q_, 256, 0, stream>>>(pos, outCtr, nbr, cnt, cntT);
    k_mlp<0><<<Q_/8, 256, 0, stream>>>(x, pos, outCtr, nbr, cnt, w0t, w1t, w2t,
            b0, b1, b2, sc0, sh0, sc1, sh1, stats, outF);
    k_bnparam<<<1, 128, 0, stream>>>(stats, cntT, g0, be0, sc0, sh0);
    k_mlp<1><<<Q_/8, 256, 0, stream>>>(x, pos, outCtr, nbr, cnt, w0t, w1t, w2t,
            b0, b1, b2, sc0, sh0, sc1, sh1, stats + 256, outF);
    k_bnparam<<<1, 128, 0, stream>>>(stats + 256, cntT, g1, be1, sc1, sh1);
    k_mlp<2><<<Q_/8, 256, 0, stream>>>(x, pos, outCtr, nbr, cnt, w0t, w1t, w2t,
            b0, b1, b2, sc0, sh0, sc1, sh1, stats, outF);
}